// Round 1
// baseline (469.882 us; speedup 1.0000x reference)
//
#include <hip/hip_runtime.h>
#include <math.h>

#define FRAME_LEN 400
#define HOP 160
#define NFFT 512
#define NBINS 257
#define NMEL 80
#define PREEMPH 0.97f
#define MEL_FLOOR 1.192092955078125e-07f

constexpr int B = 16;
constexpr int T = 480000;
constexpr int F = 1 + (T - FRAME_LEN) / HOP; // 2998

// ---------------- Kernel 1: frame -> log-mel ----------------
__global__ __launch_bounds__(256) void frame_logmel_kernel(
    const float* __restrict__ wav,   // (B, T)
    const float* __restrict__ fil,   // (257, 80)
    const float* __restrict__ win,   // (400,)
    float* __restrict__ mel_out)     // (B*F, 80)
{
    __shared__ float xbuf[FRAME_LEN];
    __shared__ float re[NFFT];
    __shared__ float im[NFFT];
    __shared__ float twc[NFFT / 2];
    __shared__ float tws[NFFT / 2];
    __shared__ float spec[NBINS];
    __shared__ float psum[3][NMEL];
    __shared__ float red[256];

    const int t = threadIdx.x;
    const int fr = blockIdx.x;          // global frame id
    const int b = fr / F;
    const int f = fr - b * F;
    const float* src = wav + (size_t)b * T + (size_t)f * HOP;

    // twiddle table: tw[j] = exp(-2*pi*i*j/512), j = 0..255
    {
        float s, c;
        sincosf(-6.28318530717958647692f * (float)t / (float)NFFT, &s, &c);
        twc[t] = c;
        tws[t] = s;
    }

    // load frame (scaled by 32768)
    float v0 = src[t] * 32768.0f;
    xbuf[t] = v0;
    float v1 = 0.0f;
    if (t < FRAME_LEN - 256) {
        v1 = src[t + 256] * 32768.0f;
        xbuf[t + 256] = v1;
    }
    red[t] = v0 + v1;
    __syncthreads();
    // block reduce for mean
    for (int s = 128; s > 0; s >>= 1) {
        if (t < s) red[t] += red[t + s];
        __syncthreads();
    }
    const float mean = red[0] * (1.0f / (float)FRAME_LEN);

    // preemphasis + window, scatter to bit-reversed positions (zero-pad to 512)
    #pragma unroll
    for (int rep = 0; rep < 2; ++rep) {
        int n = t + rep * 256;
        float val = 0.0f;
        if (n < FRAME_LEN) {
            float xn = xbuf[n] - mean;
            float p;
            if (n == 0) {
                p = xn * (1.0f - PREEMPH);
            } else {
                float xm = xbuf[n - 1] - mean;
                p = xn - PREEMPH * xm;
            }
            val = p * win[n];
        }
        int r = (int)(__brev((unsigned)n) >> 23); // 9-bit reversal
        re[r] = val;
        im[r] = 0.0f;
    }
    __syncthreads();

    // radix-2 DIT FFT, 9 stages, one butterfly per thread per stage
    #pragma unroll
    for (int s = 0; s < 9; ++s) {
        int half = 1 << s;
        int pos = t & (half - 1);
        int i0 = ((t >> s) << (s + 1)) + pos;
        int i1 = i0 + half;
        int tj = pos << (8 - s);
        float wr = twc[tj], wi = tws[tj];
        float ar = re[i0], ai = im[i0];
        float br = re[i1], bi = im[i1];
        float tr = wr * br - wi * bi;
        float ti = wr * bi + wi * br;
        re[i0] = ar + tr;
        im[i0] = ai + ti;
        re[i1] = ar - tr;
        im[i1] = ai - ti;
        __syncthreads();
    }

    // power spectrum, bins 0..256
    spec[t] = re[t] * re[t] + im[t] * im[t];
    if (t == 0) spec[NBINS - 1] = re[256] * re[256] + im[256] * im[256];
    __syncthreads();

    // mel matmul: 3 chunks of k, 80 mels each
    if (t < 240) {
        int m = t % NMEL;
        int chunk = t / NMEL;
        int k0 = chunk * 86;
        int k1 = (chunk == 2) ? NBINS : (k0 + 86);
        float acc = 0.0f;
        for (int k = k0; k < k1; ++k)
            acc = fmaf(spec[k], fil[k * NMEL + m], acc);
        psum[chunk][m] = acc;
    }
    __syncthreads();
    if (t < NMEL) {
        float melv = psum[0][t] + psum[1][t] + psum[2][t];
        melv = logf(fmaxf(melv, MEL_FLOOR));
        mel_out[(size_t)fr * NMEL + t] = melv;
    }
}

// ---------------- Kernel 2: per-(b, mel) stats over frames ----------------
__global__ __launch_bounds__(640) void stats_kernel(
    const float* __restrict__ mel,   // (B*F, 80)
    float* __restrict__ stats)       // (B, 2, 80): mean then invstd
{
    const int b = blockIdx.x;
    const int m = threadIdx.x;  // 0..79
    const int r = threadIdx.y;  // 0..7

    const float* base = mel + (size_t)b * F * NMEL + m;
    double s = 0.0, s2 = 0.0;
    for (int f = r; f < F; f += 8) {
        float v = base[(size_t)f * NMEL];
        s += (double)v;
        s2 += (double)v * (double)v;
    }
    __shared__ double sh_s[8][NMEL];
    __shared__ double sh_s2[8][NMEL];
    sh_s[r][m] = s;
    sh_s2[r][m] = s2;
    __syncthreads();
    if (r == 0) {
        for (int i = 1; i < 8; ++i) {
            s += sh_s[i][m];
            s2 += sh_s2[i][m];
        }
        double mean = s / (double)F;
        double var = (s2 - s * s / (double)F) / (double)(F - 1);
        stats[b * 2 * NMEL + m] = (float)mean;
        stats[b * 2 * NMEL + NMEL + m] = (float)(1.0 / sqrt(var + 1e-7));
    }
}

// ---------------- Kernel 3: normalize in place + attention mask ----------------
__global__ __launch_bounds__(256) void norm_mask_kernel(
    float* __restrict__ out,         // features at [0, B*F*80), mask after
    const float* __restrict__ stats)
{
    const int total = B * F * NMEL;
    const int stride = gridDim.x * blockDim.x;
    for (int e = blockIdx.x * blockDim.x + threadIdx.x; e < total; e += stride) {
        int b = e / (F * NMEL);
        int m = e % NMEL;
        float mean = stats[b * 2 * NMEL + m];
        float istd = stats[b * 2 * NMEL + NMEL + m];
        out[e] = (out[e] - mean) * istd;
    }
    const int nmask = B * (F / 2);
    float* mask = out + (size_t)B * F * NMEL;
    for (int e = blockIdx.x * blockDim.x + threadIdx.x; e < nmask; e += stride)
        mask[e] = 1.0f;
}

extern "C" void kernel_launch(void* const* d_in, const int* in_sizes, int n_in,
                              void* d_out, int out_size, void* d_ws, size_t ws_size,
                              hipStream_t stream) {
    const float* wav = (const float*)d_in[0];
    const float* fil = (const float*)d_in[1];
    const float* win = (const float*)d_in[2];
    float* out = (float*)d_out;
    float* stats = (float*)d_ws;

    // 1) frames -> log-mel, written directly into d_out (reshape is layout-identity)
    frame_logmel_kernel<<<B * F, 256, 0, stream>>>(wav, fil, win, out);

    // 2) per-(batch, mel) mean/invstd
    stats_kernel<<<B, dim3(NMEL, 8), 0, stream>>>(out, stats);

    // 3) normalize in place + mask
    norm_mask_kernel<<<2048, 256, 0, stream>>>(out, stats);
}

// Round 2
// 145.865 us; speedup vs baseline: 3.2213x; 3.2213x over previous
//
#include <hip/hip_runtime.h>
#include <math.h>

#define FRAME_LEN 400
#define HOP 160
#define NBINS 257
#define NMEL 80
#define MEL_FLOOR 1.192092955078125e-07f

constexpr int B = 16;
constexpr int T = 480000;
constexpr int F = 1 + (T - FRAME_LEN) / HOP; // 2998

// ws float layout
#define WS_TWC   0      // 255 packed stage twiddles (cos)
#define WS_TWS   256    // sin
#define WS_UNPC  512    // 256 unpack twiddles cos (W_512^k)
#define WS_UNPS  768
#define WS_K0    1024   // int[80]
#define WS_LEN   1104   // int[80]
#define WS_WGT   1216   // float[32][80] transposed compact weights
#define WS_PART  4096   // float[16][8][2][80] stats partials
#define WS_STAT  24576  // float[16][2][80] mean, invstd

__device__ __forceinline__ int SW(int i) { return i ^ (i >> 5); }

// ---------------- Kernel 0: build tables ----------------
__global__ __launch_bounds__(256) void setup_kernel(
    const float* __restrict__ fil,  // (257, 80)
    float* __restrict__ ws)
{
    const int t = threadIdx.x;
    // packed per-stage FFT twiddles: for h = 128..1, entry p in [0,h): exp(-i*pi*p/h)
    int off = 0;
    #pragma unroll
    for (int h = 128; h >= 1; h >>= 1) {
        if (t < h) {
            float ang = -3.14159265358979323846f * (float)t / (float)h;
            float s, c;
            sincosf(ang, &s, &c);
            ws[WS_TWC + off + t] = c;
            ws[WS_TWS + off + t] = s;
        }
        off += h;
    }
    // unpack twiddles W_512^k = exp(-i*pi*k/256), k = 0..255
    {
        float ang = -3.14159265358979323846f * (float)t / 256.0f;
        float s, c;
        sincosf(ang, &s, &c);
        ws[WS_UNPC + t] = c;
        ws[WS_UNPS + t] = s;
    }
    // compact sparse mel filters
    if (t < NMEL) {
        int k0 = -1, k1 = -1;
        for (int k = 0; k < NBINS; ++k) {
            float w = fil[k * NMEL + t];
            if (w > 0.0f) { if (k0 < 0) k0 = k; k1 = k; }
        }
        int len = (k0 < 0) ? 0 : (k1 - k0 + 1);
        if (len > 32) len = 32;
        if (k0 < 0) k0 = 0;
        int* wsi = (int*)ws;
        wsi[WS_K0 + t] = k0;
        wsi[WS_LEN + t] = len;
        for (int j = 0; j < 32; ++j)
            ws[WS_WGT + j * NMEL + t] = (j < len) ? fil[(k0 + j) * NMEL + t] : 0.0f;
    }
}

// ---------------- Kernel 1: frame -> log-mel ----------------
__global__ __launch_bounds__(128) void frame_logmel_kernel(
    const float* __restrict__ wav,   // (B, T)
    const float* __restrict__ win,   // (400,)
    const float* __restrict__ ws,
    float* __restrict__ mel_out)     // (B*F, 80)
{
    __shared__ float xb[FRAME_LEN];
    __shared__ float zre[256];
    __shared__ float zim[256];
    __shared__ float twc[256];
    __shared__ float tws[256];
    __shared__ float spec[NBINS];
    __shared__ float redbuf[2];

    const int t = threadIdx.x;
    const int fr = blockIdx.x;
    const int b = fr / F;
    const int f = fr - b * F;
    const float* src = wav + (size_t)b * T + (size_t)f * HOP;

    // stage twiddles -> LDS (255 entries; index 255 unused)
    twc[t] = ws[WS_TWC + t];
    twc[t + 128] = ws[WS_TWC + t + 128];
    tws[t] = ws[WS_TWS + t];
    tws[t + 128] = ws[WS_TWS + t + 128];

    // load frame + partial sum
    float s = 0.0f;
    #pragma unroll
    for (int i = t; i < FRAME_LEN; i += 128) {
        float v = src[i] * 32768.0f;
        xb[i] = v;
        s += v;
    }
    // wave reduce (64-wide), then combine 2 waves
    #pragma unroll
    for (int m = 32; m >= 1; m >>= 1) s += __shfl_xor(s, m);
    if ((t & 63) == 0) redbuf[t >> 6] = s;
    __syncthreads();
    const float mean = (redbuf[0] + redbuf[1]) * (1.0f / (float)FRAME_LEN);

    // preemph + window + pack to complex (zero-pad), natural order
    const float2* win2 = (const float2*)win;
    #pragma unroll
    for (int rep = 0; rep < 2; ++rep) {
        int n = t + rep * 128;
        float v0 = 0.0f, v1 = 0.0f;
        if (n < FRAME_LEN / 2) {  // 2n, 2n+1 < 400
            int j0 = 2 * n;
            float x0 = xb[j0];
            float xm = (j0 == 0) ? x0 : xb[j0 - 1];
            float x1 = xb[j0 + 1];
            float2 w = win2[n];
            v0 = (x0 - 0.97f * xm - 0.03f * mean) * w.x;
            v1 = (x1 - 0.97f * x0 - 0.03f * mean) * w.y;
        }
        zre[SW(n)] = v0;
        zim[SW(n)] = v1;
    }
    __syncthreads();

    // DIF radix-2 FFT-256: natural input, bit-reversed output
    int off = 0;
    #pragma unroll
    for (int h = 128; h >= 1; h >>= 1) {
        int p = t & (h - 1);
        int i0 = ((t ^ p) << 1) | p;  // (t & ~(h-1))*2 + p
        int i1 = i0 + h;
        float wr = twc[off + p], wi = tws[off + p];
        int s0 = SW(i0), s1 = SW(i1);
        float ar = zre[s0], ai = zim[s0];
        float br = zre[s1], bi = zim[s1];
        zre[s0] = ar + br;
        zim[s0] = ai + bi;
        float tr = ar - br, ti = ai - bi;
        zre[s1] = tr * wr - ti * wi;
        zim[s1] = tr * wi + ti * wr;
        off += h;
        __syncthreads();
    }

    // unpack real-FFT bins 0..255 (Z stored bit-reversed), power spectrum
    #pragma unroll
    for (int rep = 0; rep < 2; ++rep) {
        int k = t + rep * 128;
        int rk = (int)(__brev((unsigned)k) >> 24);
        int rmk = (int)(__brev((unsigned)((256 - k) & 255)) >> 24);
        int srk = SW(rk), srmk = SW(rmk);
        float ar = zre[srk], ai = zim[srk];
        float br = zre[srmk], bi = zim[srmk];
        float Er = 0.5f * (ar + br);
        float Ei = 0.5f * (ai - bi);
        float Or = 0.5f * (ai + bi);
        float Oi = 0.5f * (br - ar);
        float wr = ws[WS_UNPC + k], wi = ws[WS_UNPS + k];
        float Xr = Er + wr * Or - wi * Oi;
        float Xi = Ei + wr * Oi + wi * Or;
        spec[k] = Xr * Xr + Xi * Xi;
    }
    if (t == 0) {
        float zr = zre[0], zi = zim[0];  // Z[0] at pos 0
        float x = zr - zi;               // X[256] = Re(Z0) - Im(Z0)
        spec[256] = x * x;
    }
    __syncthreads();

    // sparse mel projection
    if (t < NMEL) {
        const int* wsi = (const int*)ws;
        int k0 = wsi[WS_K0 + t];
        int len = wsi[WS_LEN + t];
        float acc = 0.0f;
        for (int j = 0; j < len; ++j)
            acc = fmaf(spec[k0 + j], ws[WS_WGT + j * NMEL + t], acc);
        acc = logf(fmaxf(acc, MEL_FLOOR));
        mel_out[(size_t)fr * NMEL + t] = acc;
    }
}

// ---------------- Kernel 2a: stats partials ----------------
__global__ __launch_bounds__(640) void stats_partial_kernel(
    const float* __restrict__ mel,   // (B*F, 80)
    float* __restrict__ ws)
{
    const int b = blockIdx.x;
    const int c = blockIdx.y;        // chunk 0..7
    const int m = threadIdx.x;       // 0..79
    const int r = threadIdx.y;       // 0..7
    const int f0 = c * 375;
    const int f1 = (f0 + 375 < F) ? (f0 + 375) : F;

    const float* base = mel + ((size_t)b * F) * NMEL + m;
    float s = 0.0f, s2 = 0.0f;
    for (int f = f0 + r; f < f1; f += 8) {
        float v = base[(size_t)f * NMEL];
        s += v;
        s2 += v * v;
    }
    __shared__ float shs[8][NMEL];
    __shared__ float shs2[8][NMEL];
    shs[r][m] = s;
    shs2[r][m] = s2;
    __syncthreads();
    if (r == 0) {
        #pragma unroll
        for (int i = 1; i < 8; ++i) { s += shs[i][m]; s2 += shs2[i][m]; }
        float* part = ws + WS_PART;
        part[((b * 8 + c) * 2 + 0) * NMEL + m] = s;
        part[((b * 8 + c) * 2 + 1) * NMEL + m] = s2;
    }
}

// ---------------- Kernel 2b: finalize stats ----------------
__global__ __launch_bounds__(256) void stats_final_kernel(float* __restrict__ ws)
{
    const float* part = ws + WS_PART;
    float* stat = ws + WS_STAT;
    for (int i = threadIdx.x; i < B * NMEL; i += 256) {
        int b = i / NMEL, m = i - b * NMEL;
        double s = 0.0, s2 = 0.0;
        for (int c = 0; c < 8; ++c) {
            s += (double)part[((b * 8 + c) * 2 + 0) * NMEL + m];
            s2 += (double)part[((b * 8 + c) * 2 + 1) * NMEL + m];
        }
        double mean = s / (double)F;
        double var = (s2 - s * s / (double)F) / (double)(F - 1);
        stat[b * 2 * NMEL + m] = (float)mean;
        stat[b * 2 * NMEL + NMEL + m] = (float)(1.0 / sqrt(var + 1e-7));
    }
}

// ---------------- Kernel 3: normalize (float4) + mask ----------------
__global__ __launch_bounds__(256) void norm_mask_kernel(
    float* __restrict__ out,
    const float* __restrict__ ws)
{
    const float* stat = ws + WS_STAT;
    const int total4 = (B * F * NMEL) / 4;  // 959360
    const int stride = gridDim.x * blockDim.x;
    float4* out4 = (float4*)out;
    for (int e4 = blockIdx.x * blockDim.x + threadIdx.x; e4 < total4; e4 += stride) {
        int e = e4 * 4;
        int b = e / (F * NMEL);
        int m = e % NMEL;           // multiple of 4, stays within row
        const float* sb = stat + b * 2 * NMEL;
        float4 v = out4[e4];
        v.x = (v.x - sb[m + 0]) * sb[NMEL + m + 0];
        v.y = (v.y - sb[m + 1]) * sb[NMEL + m + 1];
        v.z = (v.z - sb[m + 2]) * sb[NMEL + m + 2];
        v.w = (v.w - sb[m + 3]) * sb[NMEL + m + 3];
        out4[e4] = v;
    }
    const int nmask = B * (F / 2);  // 23984
    float* mask = out + (size_t)B * F * NMEL;
    for (int e = blockIdx.x * blockDim.x + threadIdx.x; e < nmask; e += stride)
        mask[e] = 1.0f;
}

extern "C" void kernel_launch(void* const* d_in, const int* in_sizes, int n_in,
                              void* d_out, int out_size, void* d_ws, size_t ws_size,
                              hipStream_t stream) {
    const float* wav = (const float*)d_in[0];
    const float* fil = (const float*)d_in[1];
    const float* win = (const float*)d_in[2];
    float* out = (float*)d_out;
    float* ws = (float*)d_ws;

    setup_kernel<<<1, 256, 0, stream>>>(fil, ws);
    frame_logmel_kernel<<<B * F, 128, 0, stream>>>(wav, win, ws, out);
    stats_partial_kernel<<<dim3(B, 8), dim3(NMEL, 8), 0, stream>>>(out, ws);
    stats_final_kernel<<<1, 256, 0, stream>>>(ws);
    norm_mask_kernel<<<2048, 256, 0, stream>>>(out, ws);
}